// Round 14
// baseline (937.344 us; speedup 1.0000x reference)
//
#include <hip/hip_runtime.h>
#include <math.h>

// BiMambaEncoder: 8-layer bidirectional Mamba2 stack.
// Round 14: y_kernel epilogue restructured into a pass-2 (vt LDS tile) so the
// silu-gate reads z and writes ybf with coalesced int4 ops instead of scalar
// ushort ops; per-row sum-of-squares accumulated in-register across heads.
// xs_s buffer dropped (D*xs read from xsT) -> LDS unchanged, 3 blocks/CU.

namespace {

constexpr int kL = 2048;
constexpr int kDM = 256;
constexpr int kDI = 512;
constexpr int kNH = 16;
constexpr int kDS = 64;
constexpr int kCDIM = 640;
constexpr int kDPROJ = 1168;
constexpr int kCH = 64;
constexpr int kKC = 32;
constexpr int kBB = 8;
constexpr int kRowsD = 4 * kL;
constexpr int kRows = kBB * kL;

typedef __bf16 bf16x8 __attribute__((ext_vector_type(8)));
typedef float f32x4 __attribute__((ext_vector_type(4)));
typedef unsigned short ushort;

union U16x8 {
  int4 v;
  ushort u[8];
  bf16x8 b;
};

__device__ __forceinline__ ushort f2b(float x) {
  union { float f; unsigned u; } c;
  c.f = x;
  unsigned r = c.u + 0x7fffu + ((c.u >> 16) & 1u);
  return (ushort)(r >> 16);
}
__device__ __forceinline__ float b2f(ushort u) {
  union { unsigned u; float f; } c;
  c.u = ((unsigned)u) << 16;
  return c.f;
}

__device__ __forceinline__ void gl_lds16(const void* g, void* l) {
  __builtin_amdgcn_global_load_lds(
      (const __attribute__((address_space(1))) unsigned int*)g,
      (__attribute__((address_space(3))) unsigned int*)l, 16, 0, 0);
}

// ---------------- fp32 -> bf16 weight conversion: win (both dirs) + fusion ----------------
constexpr int kQwin = 8 * kDPROJ * kDM / 4;
constexpr int kQfus = kDM * kDI / 4;
constexpr int kQtot = 2 * kQwin + kQfus;

__global__ __launch_bounds__(256) void f2b_all_kernel(
    const float* __restrict__ s0, const float* __restrict__ s1,
    const float* __restrict__ s4, ushort* __restrict__ dst) {
  int i = blockIdx.x * 256 + threadIdx.x;
  if (i >= kQtot) return;
  const float* src;
  int off;
  if (i < kQwin) { src = s0; off = i; }
  else if (i < 2 * kQwin) { src = s1; off = i - kQwin; }
  else { src = s4; off = i - 2 * kQwin; }
  float4 v = *(const float4*)&src[(size_t)off * 4];
  ushort4 o = {f2b(v.x), f2b(v.y), f2b(v.z), f2b(v.w)};
  *(ushort4*)&dst[(size_t)i * 4] = o;
}

// ---------------- wout conversion with norm_w folded in ----------------
constexpr int kQwoutAll = 2 * 8 * kDM * kDI / 4;  // 524288

__global__ __launch_bounds__(256) void wout_f2b_kernel(const float* __restrict__ fw,
                                                       const float* __restrict__ bw,
                                                       const float* __restrict__ fnw,
                                                       const float* __restrict__ bnw,
                                                       ushort* __restrict__ dst) {
  int i = blockIdx.x * 256 + threadIdx.x;
  if (i >= kQwoutAll) return;
  int dl = i >> 15;
  int rem = i & 32767;
  int e4 = (rem & 127) * 4;
  const float* src = (dl < 8) ? fw : bw;
  const float* nw = (dl < 8) ? fnw : bnw;
  int layer = dl & 7;
  size_t so = (size_t)layer * kDM * kDI + (size_t)(rem >> 7) * kDI + e4;
  float4 v = *(const float4*)&src[so];
  float4 n = *(const float4*)&nw[layer * kDI + e4];
  ushort4 o = {f2b(v.x * n.x), f2b(v.y * n.y), f2b(v.z * n.z), f2b(v.w * n.w)};
  *(ushort4*)&dst[(size_t)i * 4] = o;
}

// ---------------- init: h[0..3]=x, h[4..7]=flip(x) ----------------
__global__ __launch_bounds__(256) void init_h_kernel(const float* __restrict__ x,
                                                     float* __restrict__ h) {
  int idx = blockIdx.x * 256 + threadIdx.x;
  if (idx >= 4 * kL * kDM) return;
  int d = idx & (kDM - 1);
  int l = (idx >> 8) & (kL - 1);
  int b = idx >> 19;
  float v = x[idx];
  h[idx] = v;
  h[((size_t)((4 + b) * kL + (kL - 1 - l))) * kDM + d] = v;
}

// ---------------- LayerNorm over 256, wave per row, bf16 out ----------------
__global__ __launch_bounds__(256) void ln_kernel(const float* __restrict__ h,
                                                 const float* __restrict__ w0,
                                                 const float* __restrict__ b0,
                                                 const float* __restrict__ w1,
                                                 const float* __restrict__ b1,
                                                 ushort* __restrict__ xn) {
  int t = threadIdx.x;
  int lane = t & 63;
  int row = blockIdx.x * 4 + (t >> 6);
  int dir = (row >= kRowsD) ? 1 : 0;
  const float* w = dir ? w1 : w0;
  const float* b = dir ? b1 : b0;
  int e0 = lane * 4;
  float4 v = *(const float4*)&h[(size_t)row * kDM + e0];
  float s = v.x + v.y + v.z + v.w;
#pragma unroll
  for (int o = 32; o > 0; o >>= 1) s += __shfl_xor(s, o);
  float mu = s * (1.0f / kDM);
  float4 d = {v.x - mu, v.y - mu, v.z - mu, v.w - mu};
  float ss = d.x * d.x + d.y * d.y + d.z * d.z + d.w * d.w;
#pragma unroll
  for (int o = 32; o > 0; o >>= 1) ss += __shfl_xor(ss, o);
  float r = rsqrtf(ss * (1.0f / kDM) + 1e-5f);
  float4 wv = *(const float4*)&w[e0];
  float4 bv = *(const float4*)&b[e0];
  ushort4 o = {f2b(d.x * r * wv.x + bv.x), f2b(d.y * r * wv.y + bv.y),
               f2b(d.z * r * wv.z + bv.z), f2b(d.w * r * wv.w + bv.w)};
  *(ushort4*)&xn[(size_t)row * kDM + e0] = o;
}

// ---------------- 128x128 bf16 MFMA GEMM (in_proj), BK=64, XCD m-major ----------------
__global__ __launch_bounds__(256) void gemm_bf16(const ushort* __restrict__ A,
                                                 const ushort* __restrict__ W0,
                                                 const ushort* __restrict__ W1,
                                                 ushort* __restrict__ C16,
                                                 float* __restrict__ dtraw, int Md,
                                                 int N, int K, int NT) {
  int dir = blockIdx.z;
  const ushort* W = dir ? W1 : W0;
  const ushort* Ab = A + (size_t)dir * Md * K;
  int wg = blockIdx.x;
  int chunk = gridDim.x >> 3;
  int swz = (wg & 7) * chunk + (wg >> 3);
  int m0 = (swz / NT) * 128;
  int n0 = (swz % NT) * 128;
  __shared__ __align__(16) ushort As[2][128 * 32];
  __shared__ __align__(16) ushort Ws[2][128 * 32];
  int tid = threadIdx.x;
  int lane = tid & 63;
  int wv = tid >> 6;
  int wr = (wv >> 1) * 64, wc = (wv & 1) * 64;
  int l16 = lane & 15, lk = lane >> 4;
  int rA = tid >> 2;
  int cA = (tid & 3) * 8;
  int rb0 = n0 + rA;       if (rb0 >= N) rb0 = N - 1;
  int rb1 = n0 + rA + 64;  if (rb1 >= N) rb1 = N - 1;

  f32x4 acc[4][4];
#pragma unroll
  for (int m = 0; m < 4; m++)
#pragma unroll
    for (int n = 0; n < 4; n++) acc[m][n] = {0.f, 0.f, 0.f, 0.f};

  for (int k0 = 0; k0 < K; k0 += 64) {
#pragma unroll
    for (int hh = 0; hh < 2; hh++) {
      int kk = k0 + hh * 32;
      gl_lds16(Ab + (size_t)(m0 + rA) * K + kk + cA, (char*)As[hh] + wv * 1024);
      gl_lds16(Ab + (size_t)(m0 + rA + 64) * K + kk + cA,
               (char*)As[hh] + 4096 + wv * 1024);
      gl_lds16(W + (size_t)rb0 * K + kk + cA, (char*)Ws[hh] + wv * 1024);
      gl_lds16(W + (size_t)rb1 * K + kk + cA, (char*)Ws[hh] + 4096 + wv * 1024);
    }
    __syncthreads();
#pragma unroll
    for (int hh = 0; hh < 2; hh++) {
      bf16x8 a[4], b[4];
#pragma unroll
      for (int m = 0; m < 4; m++)
        a[m] = *(const bf16x8*)((const char*)As[hh] +
                                (((wr + m * 16 + l16) * 32 + lk * 8) << 1));
#pragma unroll
      for (int n = 0; n < 4; n++)
        b[n] = *(const bf16x8*)((const char*)Ws[hh] +
                                (((wc + n * 16 + l16) * 32 + lk * 8) << 1));
#pragma unroll
      for (int m = 0; m < 4; m++)
#pragma unroll
        for (int n = 0; n < 4; n++)
          acc[m][n] =
              __builtin_amdgcn_mfma_f32_16x16x32_bf16(a[m], b[n], acc[m][n], 0, 0, 0);
    }
    __syncthreads();
  }
  ushort* Cb = C16 + (size_t)dir * Md * N;
  float* dtb = dtraw + (size_t)dir * Md * kNH;
#pragma unroll
  for (int m = 0; m < 4; m++) {
#pragma unroll
    for (int n = 0; n < 4; n++) {
      int col = n0 + wc + n * 16 + l16;
      if (col < N) {
#pragma unroll
        for (int r = 0; r < 4; r++) {
          int row = m0 + wr + m * 16 + lk * 4 + r;
          float v = acc[m][n][r];
          Cb[(size_t)row * N + col] = f2b(v);
          if (col >= 2 * kDI + 2 * kDS)
            dtb[(size_t)row * kNH + (col - (2 * kDI + 2 * kDS))] = v;
        }
      }
    }
  }
}

// ---------------- 64x64 bf16 MFMA GEMM (out_proj / fusion), BK=64 ----------------
__global__ __launch_bounds__(256) void gemm_bf16_64(const ushort* __restrict__ A,
                                                    const ushort* __restrict__ W0,
                                                    const ushort* __restrict__ W1,
                                                    float* __restrict__ C,
                                                    const float* __restrict__ rsum,
                                                    int Md, int N, int K, int NT,
                                                    int accumulate) {
  int dir = blockIdx.z;
  const ushort* W = dir ? W1 : W0;
  const ushort* Ab = A + (size_t)dir * Md * K;
  float* Cb = C + (size_t)dir * Md * N;
  int wg = blockIdx.x;
  int chunk = gridDim.x >> 3;
  int swz = (wg & 7) * chunk + (wg >> 3);
  int m0 = (swz / NT) * 64;
  int n0 = (swz % NT) * 64;
  __shared__ __align__(16) ushort As[2][64 * 32];
  __shared__ __align__(16) ushort Ws[2][64 * 32];
  int tid = threadIdx.x;
  int lane = tid & 63;
  int wv = tid >> 6;
  int wr = (wv >> 1) * 32, wc = (wv & 1) * 32;
  int l16 = lane & 15, lk = lane >> 4;
  int rA = tid >> 2;
  int cA = (tid & 3) * 8;

  f32x4 acc[2][2];
#pragma unroll
  for (int m = 0; m < 2; m++)
#pragma unroll
    for (int n = 0; n < 2; n++) acc[m][n] = {0.f, 0.f, 0.f, 0.f};

  for (int k0 = 0; k0 < K; k0 += 64) {
#pragma unroll
    for (int hh = 0; hh < 2; hh++) {
      int kk = k0 + hh * 32;
      gl_lds16(Ab + (size_t)(m0 + rA) * K + kk + cA, (char*)As[hh] + wv * 1024);
      gl_lds16(W + (size_t)(n0 + rA) * K + kk + cA, (char*)Ws[hh] + wv * 1024);
    }
    __syncthreads();
#pragma unroll
    for (int hh = 0; hh < 2; hh++) {
      bf16x8 a[2], b[2];
#pragma unroll
      for (int m = 0; m < 2; m++)
        a[m] = *(const bf16x8*)((const char*)As[hh] +
                                (((wr + m * 16 + l16) * 32 + lk * 8) << 1));
#pragma unroll
      for (int n = 0; n < 2; n++)
        b[n] = *(const bf16x8*)((const char*)Ws[hh] +
                                (((wc + n * 16 + l16) * 32 + lk * 8) << 1));
#pragma unroll
      for (int m = 0; m < 2; m++)
#pragma unroll
        for (int n = 0; n < 2; n++)
          acc[m][n] =
              __builtin_amdgcn_mfma_f32_16x16x32_bf16(a[m], b[n], acc[m][n], 0, 0, 0);
    }
    __syncthreads();
  }
#pragma unroll
  for (int m = 0; m < 2; m++) {
#pragma unroll
    for (int r = 0; r < 4; r++) {
      int row = m0 + wr + m * 16 + lk * 4 + r;
      float sc = 1.f;
      if (accumulate)
        sc = rsqrtf(rsum[(size_t)dir * Md + row] * (1.0f / kDI) + 1e-5f);
#pragma unroll
      for (int n = 0; n < 2; n++) {
        int col = n0 + wc + n * 16 + l16;
        size_t idx = (size_t)row * N + col;
        float v = acc[m][n][r];
        if (accumulate) Cb[idx] += sc * v;
        else Cb[idx] = v;
      }
    }
  }
}

// ---------------- merged: conv+silu (8 ch/thread) | softplus+cumsum ----------------
constexpr int kConvBlocks = (kRows / 16) * (kCDIM / 8) / 256;  // 320

__global__ __launch_bounds__(256) void conv_cumsum_kernel(
    const ushort* __restrict__ zxb, const float* __restrict__ cw0,
    const float* __restrict__ cb0, const float* __restrict__ cw1,
    const float* __restrict__ cb1, ushort* __restrict__ xcb,
    const float* __restrict__ dtraw, const float* __restrict__ db0,
    const float* __restrict__ db1, const float* __restrict__ al0,
    const float* __restrict__ al1, float* __restrict__ dt,
    float* __restrict__ cs, float* __restrict__ g) {
  if ((int)blockIdx.x < kConvBlocks) {
    constexpr int kCG = kCDIM / 8;  // 80 channel groups
    int idx = blockIdx.x * 256 + threadIdx.x;
    int c8 = (idx % kCG) * 8;
    int rt = idx / kCG;
    int bb = rt >> 7;
    int l0 = (rt & 127) << 4;
    int dir = bb >> 2;
    const float* cw = dir ? cw1 : cw0;
    const float* cb = dir ? cb1 : cb0;
    float wt[8][4];
#pragma unroll
    for (int c = 0; c < 8; c++) {
      float4 w = *(const float4*)&cw[(c8 + c) * 4];
      wt[c][0] = w.x; wt[c][1] = w.y; wt[c][2] = w.z; wt[c][3] = w.w;
    }
    float bias[8];
    {
      float4 b0 = *(const float4*)&cb[c8];
      float4 b1 = *(const float4*)&cb[c8 + 4];
      bias[0] = b0.x; bias[1] = b0.y; bias[2] = b0.z; bias[3] = b0.w;
      bias[4] = b1.x; bias[5] = b1.y; bias[6] = b1.z; bias[7] = b1.w;
    }
    const ushort* base = zxb + ((size_t)(bb * kL)) * kDPROJ + kDI + c8;
    float w0[8], w1[8], w2[8];
    if (l0 == 0) {
#pragma unroll
      for (int c = 0; c < 8; c++) { w0[c] = 0.f; w1[c] = 0.f; w2[c] = 0.f; }
    } else {
      U16x8 a, b, c;
      a.v = *(const int4*)(base + (size_t)(l0 - 3) * kDPROJ);
      b.v = *(const int4*)(base + (size_t)(l0 - 2) * kDPROJ);
      c.v = *(const int4*)(base + (size_t)(l0 - 1) * kDPROJ);
#pragma unroll
      for (int q = 0; q < 8; q++) {
        w0[q] = b2f(a.u[q]); w1[q] = b2f(b.u[q]); w2[q] = b2f(c.u[q]);
      }
    }
    ushort* outp = xcb + (size_t)(bb * kL + l0) * kCDIM + c8;
#pragma unroll
    for (int r = 0; r < 16; r++) {
      U16x8 cu;
      cu.v = *(const int4*)(base + (size_t)(l0 + r) * kDPROJ);
      U16x8 o;
#pragma unroll
      for (int c = 0; c < 8; c++) {
        float cf = b2f(cu.u[c]);
        float a = bias[c] + wt[c][0] * w0[c] + wt[c][1] * w1[c] + wt[c][2] * w2[c] +
                  wt[c][3] * cf;
        o.u[c] = f2b(a / (1.f + __expf(-a)));
        w0[c] = w1[c];
        w1[c] = w2[c];
        w2[c] = cf;
      }
      *(int4*)(outp + (size_t)r * kCDIM) = o.v;
    }
  } else {
    int t = threadIdx.x;
    int c = t & 63;
    int wid = ((int)blockIdx.x - kConvBlocks) * 4 + (t >> 6);
    int h = wid & (kNH - 1);
    int k = (wid >> 4) & (kKC - 1);
    int bb = wid >> 9;
    int dir = bb >> 2;
    int row = bb * kL + k * kCH + c;
    float x = dtraw[(size_t)row * kNH + h] + (dir ? db1 : db0)[h];
    float dtv = (x > 20.f) ? x : log1pf(expf(x));
    dt[(size_t)row * kNH + h] = dtv;
    float A = -__expf((dir ? al1 : al0)[h]);
    float s = dtv * A;
#pragma unroll
    for (int off = 1; off < 64; off <<= 1) {
      float u = __shfl_up(s, off);
      if (c >= off) s += u;
    }
    cs[(size_t)wid * kCH + c] = s;
    if (c == 63) g[wid] = __expf(s);
  }
}

// ---------------- MFMA states: 2 blocks per (b,k), wave per head; bf16 out ----------------
__global__ __launch_bounds__(256) void states_kernel(const ushort* __restrict__ xcb,
                                                     const float* __restrict__ dt,
                                                     const float* __restrict__ cs,
                                                     ushort* __restrict__ states) {
  int bid = blockIdx.x;
  int half = bid & 1;
  int bk = bid >> 1;
  int k = bk & (kKC - 1);
  int bb = bk >> 5;
  __shared__ __align__(16) ushort Bstage[64][72];
  __shared__ __align__(16) ushort Bt[64][72];
  __shared__ __align__(16) ushort Ap[4][32][72];
  __shared__ float w_s[8][64];
  int t = threadIdx.x;
  int lane = t & 63, wv = t >> 6;
  size_t rowbase = (size_t)(bb * kL + k * kCH);
  {
    int j = t >> 2, n0 = (t & 3) * 16;
    const ushort* src = xcb + (rowbase + j) * kCDIM + kDI + n0;
    *(int4*)&Bstage[j][n0] = *(const int4*)src;
    *(int4*)&Bstage[j][n0 + 8] = *(const int4*)(src + 8);
  }
#pragma unroll
  for (int i = 0; i < 2; i++) {
    int e = t + i * 256;
    int hl = e >> 6, c = e & 63;
    int h = half * 8 + hl;
    const float* csb = cs + ((size_t)bk * 16 + h) * kCH;
    w_s[hl][c] = __expf(csb[63] - csb[c]) * dt[(rowbase + c) * kNH + h];
  }
  __syncthreads();
#pragma unroll
  for (int i = 0; i < 16; i++) {
    int e = t + i * 256;
    int j = e & 63, n = e >> 6;
    Bt[n][j] = Bstage[j][n];
  }
  __syncthreads();
  int l15 = lane & 15, lk8 = (lane >> 4) * 8;
  for (int hg = 0; hg < 2; hg++) {
    int hl = hg * 4 + wv;
    int h = half * 8 + hl;
    float wl = w_s[hl][lane];
    const ushort* xrow = xcb + (rowbase + lane) * kCDIM + h * 32;
#pragma unroll
    for (int q4 = 0; q4 < 4; q4++) {
      U16x8 v;
      v.v = *(const int4*)(xrow + q4 * 8);
#pragma unroll
      for (int q = 0; q < 8; q++)
        Ap[wv][q4 * 8 + q][lane] = f2b(b2f(v.u[q]) * wl);
    }
#pragma unroll
    for (int pt = 0; pt < 2; pt++) {
#pragma unroll
      for (int nt = 0; nt < 4; nt++) {
        f32x4 acc = {0.f, 0.f, 0.f, 0.f};
#pragma unroll
        for (int kt = 0; kt < 2; kt++) {
          bf16x8 a = *(const bf16x8*)&Ap[wv][pt * 16 + l15][kt * 32 + lk8];
          bf16x8 b = *(const bf16x8*)&Bt[nt * 16 + l15][kt * 32 + lk8];
          acc = __builtin_amdgcn_mfma_f32_16x16x32_bf16(a, b, acc, 0, 0, 0);
        }
        size_t base = ((size_t)bk * 16 + h) * 2048;
#pragma unroll
        for (int r = 0; r < 4; r++) {
          int p = pt * 16 + (lane >> 4) * 4 + r;
          states[base + p * 64 + nt * 16 + l15] = f2b(acc[r]);
        }
      }
    }
  }
}

// ---------------- chunk scan (x4, prefetched) + rsum zeroing ----------------
__global__ __launch_bounds__(256) void scan_kernel(const ushort* __restrict__ st,
                                                   const float* __restrict__ g,
                                                   ushort* __restrict__ spbf,
                                                   float* __restrict__ rsum) {
  if ((int)blockIdx.x >= 256) {
    int i2 = ((int)blockIdx.x - 256) * 1024 + threadIdx.x * 4;
    float4 z = {0.f, 0.f, 0.f, 0.f};
    *(float4*)&rsum[i2] = z;
    return;
  }
  int idx = blockIdx.x * 256 + threadIdx.x;
  int pn4 = (idx & 511) * 4;
  int h = (idx >> 9) & (kNH - 1);
  int bb = idx >> 13;
  size_t base = ((size_t)(bb * kKC) * kNH + h) * 2048 + pn4;
  size_t stride = (size_t)kNH * 2048;
  const float* gp = g + bb * kKC * kNH + h;
  float S[4] = {0.f, 0.f, 0.f, 0.f};
  ushort4 sv = *(const ushort4*)&st[base];
  float gk = gp[0];
  for (int k = 0; k < kKC; k++) {
    size_t off = base + (size_t)k * stride;
    ushort4 so = {f2b(S[0]), f2b(S[1]), f2b(S[2]), f2b(S[3])};
    *(ushort4*)&spbf[off] = so;
    ushort4 nxt;
    float gn = 0.f;
    if (k < kKC - 1) {
      nxt = *(const ushort4*)&st[off + stride];
      gn = gp[(k + 1) * kNH];
    }
    S[0] = gk * S[0] + b2f(sv.x);
    S[1] = gk * S[1] + b2f(sv.y);
    S[2] = gk * S[2] + b2f(sv.z);
    S[3] = gk * S[3] + b2f(sv.w);
    sv = nxt;
    gk = gn;
  }
}

// ---------------- fused y + silu-gate (pass-2 coalesced): 4 blocks per (b,k) ----------------
__global__ __launch_bounds__(256) void y_kernel(const ushort* __restrict__ xcb,
                                                const ushort* __restrict__ zxb,
                                                const float* __restrict__ dt,
                                                const float* __restrict__ cs,
                                                const ushort* __restrict__ spbf,
                                                const float* __restrict__ D0,
                                                const float* __restrict__ D1,
                                                float* __restrict__ rsum,
                                                ushort* __restrict__ ybf) {
  int bid = blockIdx.x;
  int hq = bid & 3;
  int bk = bid >> 2;
  int k = bk & (kKC - 1);
  int bb = bk >> 5;
  int dir = bb >> 2;
  __shared__ __align__(16) ushort Cls[64][72];
  __shared__ __align__(16) ushort Bls[64][72];
  __shared__ float CBT[64][67];
  __shared__ __align__(16) ushort xsT[32][72];
  __shared__ __align__(16) ushort sp_s[32][72];
  __shared__ __align__(16) ushort vt[64][40];
  __shared__ float cs_s[64], dt_s[64], ecs_s[64];
  int t = threadIdx.x, lane = t & 63, wv = t >> 6;
  int l15 = lane & 15, lk8 = (lane >> 4) * 8;
  size_t rowbase = (size_t)(bb * kL + k * kCH);
  {
    int j = t >> 2, n0 = (t & 3) * 16;
    const ushort* pB = xcb + (rowbase + j) * kCDIM + kDI;
    *(int4*)&Bls[j][n0] = *(const int4*)(pB + n0);
    *(int4*)&Bls[j][n0 + 8] = *(const int4*)(pB + n0 + 8);
    *(int4*)&Cls[j][n0] = *(const int4*)(pB + kDS + n0);
    *(int4*)&Cls[j][n0 + 8] = *(const int4*)(pB + kDS + n0 + 8);
  }
  __syncthreads();
  {
    int i0 = wv * 16;
#pragma unroll
    for (int jt = 0; jt < 4; jt++) {
      f32x4 acc = {0.f, 0.f, 0.f, 0.f};
#pragma unroll
      for (int kt = 0; kt < 2; kt++) {
        bf16x8 a = *(const bf16x8*)&Cls[i0 + l15][kt * 32 + lk8];
        bf16x8 b = *(const bf16x8*)&Bls[jt * 16 + l15][kt * 32 + lk8];
        acc = __builtin_amdgcn_mfma_f32_16x16x32_bf16(a, b, acc, 0, 0, 0);
      }
#pragma unroll
      for (int r = 0; r < 4; r++)
        CBT[jt * 16 + l15][i0 + (lane >> 4) * 4 + r] = acc[r];
    }
  }
  int jrow = t >> 2, p0e = (t & 3) * 8;
  float ssr = 0.f;  // per-thread Sum(val^2) for row jrow, cols p0e..p0e+7, all heads
  for (int hi = 0; hi < 4; hi++) {
    int h = hq * 4 + hi;
    int bkh = bk * 16 + h;
    float Dp = (dir ? D1 : D0)[h];
    __syncthreads();
    {
      int j = t >> 2, p0 = (t & 3) * 8;
      U16x8 v;
      v.v = *(const int4*)(xcb + (rowbase + j) * kCDIM + h * 32 + p0);
#pragma unroll
      for (int q = 0; q < 8; q++) xsT[p0 + q][j] = v.u[q];
      int4 s = *(const int4*)(spbf + (size_t)bkh * 2048 + t * 8);
      *(int4*)&sp_s[t >> 3][(t & 7) * 8] = s;
      if (t < 64) {
        float cv = cs[(size_t)bkh * kCH + t];
        cs_s[t] = cv;
        ecs_s[t] = __expf(cv);
        dt_s[t] = dt[(rowbase + t) * kNH + h];
      }
    }
    __syncthreads();
    int i0 = wv * 16;
    int ia = i0 + l15;
    float csi = cs_s[ia];
    U16x8 af[2];
#pragma unroll
    for (int kt = 0; kt < 2; kt++) {
#pragma unroll
      for (int q = 0; q < 8; q++) {
        int j = kt * 32 + lk8 + q;
        float v = 0.f;
        if (j <= ia) v = __expf(csi - cs_s[j]) * dt_s[j] * CBT[j][ia];
        af[kt].u[q] = f2b(v);
      }
    }
#pragma unroll
    for (int pt = 0; pt < 2; pt++) {
      f32x4 acc = {0.f, 0.f, 0.f, 0.f};
      f32x4 acc2 = {0.f, 0.f, 0.f, 0.f};
#pragma unroll
      for (int kt = 0; kt < 2; kt++) {
        bf16x8 bx = *(const bf16x8*)&xsT[pt * 16 + l15][kt * 32 + lk8];
        acc = __builtin_amdgcn_mfma_f32_16x16x32_bf16(af[kt].b, bx, acc, 0, 0, 0);
        bf16x8 ac = *(const bf16x8*)&Cls[i0 + l15][kt * 32 + lk8];
        bf16x8 bs = *(const bf16x8*)&sp_s[pt * 16 + l15][kt * 32 + lk8];
        acc2 = __builtin_amdgcn_mfma_f32_16x16x32_bf16(ac, bs, acc2, 0, 0, 0);
      }
      int p = pt * 16 + l15;
#pragma unroll
      for (int r = 0; r < 4; r++) {
        int io = i0 + (lane >> 4) * 4 + r;
        float xsv = b2f(xsT[p][io]);
        float v = acc[r] + ecs_s[io] * acc2[r] + Dp * xsv;
        vt[io][p] = f2b(v);
      }
    }
    __syncthreads();
    // pass 2: coalesced gate + store + ss accumulation
    {
      U16x8 vv, zz, o;
      vv.v = *(const int4*)&vt[jrow][p0e];
      zz.v = *(const int4*)(zxb + (rowbase + jrow) * kDPROJ + h * 32 + p0e);
#pragma unroll
      for (int q = 0; q < 8; q++) {
        float z = b2f(zz.u[q]);
        float gz = z / (1.f + __expf(-z));
        float val = b2f(vv.u[q]) * gz;
        o.u[q] = f2b(val);
        ssr += val * val;
      }
      *(int4*)&ybf[(rowbase + jrow) * kDI + h * 32 + p0e] = o.v;
    }
  }
  // reduce ssr across the 4 threads sharing row jrow; one atomic per row.
  ssr += __shfl_xor(ssr, 1);
  ssr += __shfl_xor(ssr, 2);
  if ((t & 3) == 0) atomicAdd(&rsum[rowbase + jrow], ssr);
}

// ---------------- hcat bf16 ----------------
__global__ __launch_bounds__(256) void concat_kernel(const float* __restrict__ h,
                                                     ushort* __restrict__ hcat) {
  int idx = blockIdx.x * 256 + threadIdx.x;
  if (idx >= 4 * kL * 2 * kDM) return;
  int e = idx & 511;
  int l = (idx >> 9) & (kL - 1);
  int b = idx >> 20;
  float v;
  if (e < kDM)
    v = h[((size_t)(b * kL + l)) * kDM + e];
  else
    v = h[((size_t)((4 + b) * kL + (kL - 1 - l))) * kDM + (e - kDM)];
  hcat[idx] = f2b(v);
}

}  // namespace

extern "C" void kernel_launch(void* const* d_in, const int* in_sizes, int n_in,
                              void* d_out, int out_size, void* d_ws, size_t ws_size,
                              hipStream_t stream) {
  const float* x = (const float*)d_in[0];
  const float* fw_ln_w = (const float*)d_in[1];
  const float* fw_ln_b = (const float*)d_in[2];
  const float* fw_win = (const float*)d_in[3];
  const float* fw_convw = (const float*)d_in[4];
  const float* fw_convb = (const float*)d_in[5];
  const float* fw_alog = (const float*)d_in[6];
  const float* fw_dtb = (const float*)d_in[7];
  const float* fw_D = (const float*)d_in[8];
  const float* fw_nw = (const float*)d_in[9];
  const float* fw_wout = (const float*)d_in[10];
  const float* bw_ln_w = (const float*)d_in[11];
  const float* bw_ln_b = (const float*)d_in[12];
  const float* bw_win = (const float*)d_in[13];
  const float* bw_convw = (const float*)d_in[14];
  const float* bw_convb = (const float*)d_in[15];
  const float* bw_alog = (const float*)d_in[16];
  const float* bw_dtb = (const float*)d_in[17];
  const float* bw_D = (const float*)d_in[18];
  const float* bw_nw = (const float*)d_in[19];
  const float* bw_wout = (const float*)d_in[20];
  const float* fusion_w = (const float*)d_in[21];
  float* out = (float*)d_out;

  float* ws = (float*)d_ws;
  float* h = ws;                                   // 16384*256 f32
  float* dtraw = h + (size_t)kRows * kDM;          // 16384*16 f32
  float* dt = dtraw + (size_t)kRows * kNH;         // 16384*16 f32
  float* cs = dt + (size_t)kRows * kNH;            // 4096*64 f32
  float* g = cs + (size_t)kBB * kKC * kNH * kCH;   // 4096 f32
  float* rsum = g + (size_t)kBB * kKC * kNH;       // 16384 f32
  ushort* zxb = (ushort*)(rsum + kRows);           // 16384*1168 bf16
  ushort* xcb = zxb + (size_t)kRows * kDPROJ;      // 16384*640
  ushort* states = xcb + (size_t)kRows * kCDIM;    // 4096*2048
  ushort* spbf = states + (size_t)kBB * kKC * kNH * 2048;  // 4096*2048
  ushort* xnbf = spbf + (size_t)kBB * kKC * kNH * 2048;    // 16384*256 (also hcat)
  ushort* ybf = xnbf + (size_t)kRows * kDM;                // 16384*512
  ushort* winbf = ybf + (size_t)kRows * kDI;               // 2*8*1168*256 (+fusion)
  ushort* fusbf = winbf + (size_t)2 * 8 * kDPROJ * kDM;    // 256*512
  ushort* woutbf = fusbf + (size_t)kDM * kDI;              // 2*8*256*512
  ushort* hcatbf = xnbf;

  f2b_all_kernel<<<(kQtot + 255) / 256, 256, 0, stream>>>(fw_win, bw_win, fusion_w,
                                                          winbf);
  wout_f2b_kernel<<<(kQwoutAll + 255) / 256, 256, 0, stream>>>(fw_wout, bw_wout,
                                                               fw_nw, bw_nw, woutbf);
  init_h_kernel<<<(4 * kL * kDM + 255) / 256, 256, 0, stream>>>(x, h);

  for (int i = 0; i < 8; i++) {
    const size_t oLN = (size_t)i * kDM;
    const size_t oCW = (size_t)i * kCDIM * 4;
    const size_t oCB = (size_t)i * kCDIM;
    const size_t oH = (size_t)i * kNH;
    const ushort* win0 = winbf + (size_t)i * kDPROJ * kDM;
    const ushort* win1 = winbf + (size_t)(8 + i) * kDPROJ * kDM;
    const ushort* wout0 = woutbf + (size_t)i * kDM * kDI;
    const ushort* wout1 = woutbf + (size_t)(8 + i) * kDM * kDI;

    ln_kernel<<<kRows / 4, 256, 0, stream>>>(h, fw_ln_w + oLN, fw_ln_b + oLN,
                                             bw_ln_w + oLN, bw_ln_b + oLN, xnbf);
    {
      dim3 grid(10 * 64, 1, 2);
      gemm_bf16<<<grid, 256, 0, stream>>>(xnbf, win0, win1, zxb, dtraw, kRowsD,
                                          kDPROJ, kDM, 10);
    }
    {
      int cumsumBlocks = kBB * kKC * kNH / 4;
      conv_cumsum_kernel<<<kConvBlocks + cumsumBlocks, 256, 0, stream>>>(
          zxb, fw_convw + oCW, fw_convb + oCB, bw_convw + oCW, bw_convb + oCB, xcb,
          dtraw, fw_dtb + oH, bw_dtb + oH, fw_alog + oH, bw_alog + oH, dt, cs, g);
    }
    states_kernel<<<kBB * kKC * 2, 256, 0, stream>>>(xcb, dt, cs, states);
    scan_kernel<<<256 + 16, 256, 0, stream>>>(states, g, spbf, rsum);
    y_kernel<<<kBB * kKC * 4, 256, 0, stream>>>(xcb, zxb, dt, cs, spbf, fw_D + oH,
                                                bw_D + oH, rsum, ybf);
    {
      dim3 grid(4 * 128, 1, 2);
      gemm_bf16_64<<<grid, 256, 0, stream>>>(ybf, wout0, wout1, h, rsum, kRowsD,
                                             kDM, kDI, 4, 1);
    }
  }

  concat_kernel<<<(4 * kL * 2 * kDM + 255) / 256, 256, 0, stream>>>(h, hcatbf);
  {
    dim3 grid(4 * 128, 1, 1);
    gemm_bf16_64<<<grid, 256, 0, stream>>>(hcatbf, fusbf, fusbf, out, nullptr,
                                           kRowsD, kDM, 2 * kDM, 4, 0);
  }
}

// Round 15
// 910.950 us; speedup vs baseline: 1.0290x; 1.0290x over previous
//
#include <hip/hip_runtime.h>
#include <math.h>

// BiMambaEncoder: 8-layer bidirectional Mamba2 stack.
// Round 15: exact revert to round-13 (best: 911 us). Round-14 pass-2 epilogue
// regressed (+26 us: extra barrier/head + transposed scalar LDS reads).

namespace {

constexpr int kL = 2048;
constexpr int kDM = 256;
constexpr int kDI = 512;
constexpr int kNH = 16;
constexpr int kDS = 64;
constexpr int kCDIM = 640;
constexpr int kDPROJ = 1168;
constexpr int kCH = 64;
constexpr int kKC = 32;
constexpr int kBB = 8;
constexpr int kRowsD = 4 * kL;
constexpr int kRows = kBB * kL;

typedef __bf16 bf16x8 __attribute__((ext_vector_type(8)));
typedef float f32x4 __attribute__((ext_vector_type(4)));
typedef unsigned short ushort;

union U16x8 {
  int4 v;
  ushort u[8];
  bf16x8 b;
};

__device__ __forceinline__ ushort f2b(float x) {
  union { float f; unsigned u; } c;
  c.f = x;
  unsigned r = c.u + 0x7fffu + ((c.u >> 16) & 1u);
  return (ushort)(r >> 16);
}
__device__ __forceinline__ float b2f(ushort u) {
  union { unsigned u; float f; } c;
  c.u = ((unsigned)u) << 16;
  return c.f;
}

__device__ __forceinline__ void gl_lds16(const void* g, void* l) {
  __builtin_amdgcn_global_load_lds(
      (const __attribute__((address_space(1))) unsigned int*)g,
      (__attribute__((address_space(3))) unsigned int*)l, 16, 0, 0);
}

// ---------------- fp32 -> bf16 weight conversion: win (both dirs) + fusion ----------------
constexpr int kQwin = 8 * kDPROJ * kDM / 4;
constexpr int kQfus = kDM * kDI / 4;
constexpr int kQtot = 2 * kQwin + kQfus;

__global__ __launch_bounds__(256) void f2b_all_kernel(
    const float* __restrict__ s0, const float* __restrict__ s1,
    const float* __restrict__ s4, ushort* __restrict__ dst) {
  int i = blockIdx.x * 256 + threadIdx.x;
  if (i >= kQtot) return;
  const float* src;
  int off;
  if (i < kQwin) { src = s0; off = i; }
  else if (i < 2 * kQwin) { src = s1; off = i - kQwin; }
  else { src = s4; off = i - 2 * kQwin; }
  float4 v = *(const float4*)&src[(size_t)off * 4];
  ushort4 o = {f2b(v.x), f2b(v.y), f2b(v.z), f2b(v.w)};
  *(ushort4*)&dst[(size_t)i * 4] = o;
}

// ---------------- wout conversion with norm_w folded in ----------------
constexpr int kQwoutAll = 2 * 8 * kDM * kDI / 4;  // 524288

__global__ __launch_bounds__(256) void wout_f2b_kernel(const float* __restrict__ fw,
                                                       const float* __restrict__ bw,
                                                       const float* __restrict__ fnw,
                                                       const float* __restrict__ bnw,
                                                       ushort* __restrict__ dst) {
  int i = blockIdx.x * 256 + threadIdx.x;
  if (i >= kQwoutAll) return;
  int dl = i >> 15;
  int rem = i & 32767;
  int e4 = (rem & 127) * 4;
  const float* src = (dl < 8) ? fw : bw;
  const float* nw = (dl < 8) ? fnw : bnw;
  int layer = dl & 7;
  size_t so = (size_t)layer * kDM * kDI + (size_t)(rem >> 7) * kDI + e4;
  float4 v = *(const float4*)&src[so];
  float4 n = *(const float4*)&nw[layer * kDI + e4];
  ushort4 o = {f2b(v.x * n.x), f2b(v.y * n.y), f2b(v.z * n.z), f2b(v.w * n.w)};
  *(ushort4*)&dst[(size_t)i * 4] = o;
}

// ---------------- init: h[0..3]=x, h[4..7]=flip(x) ----------------
__global__ __launch_bounds__(256) void init_h_kernel(const float* __restrict__ x,
                                                     float* __restrict__ h) {
  int idx = blockIdx.x * 256 + threadIdx.x;
  if (idx >= 4 * kL * kDM) return;
  int d = idx & (kDM - 1);
  int l = (idx >> 8) & (kL - 1);
  int b = idx >> 19;
  float v = x[idx];
  h[idx] = v;
  h[((size_t)((4 + b) * kL + (kL - 1 - l))) * kDM + d] = v;
}

// ---------------- LayerNorm over 256, wave per row, bf16 out ----------------
__global__ __launch_bounds__(256) void ln_kernel(const float* __restrict__ h,
                                                 const float* __restrict__ w0,
                                                 const float* __restrict__ b0,
                                                 const float* __restrict__ w1,
                                                 const float* __restrict__ b1,
                                                 ushort* __restrict__ xn) {
  int t = threadIdx.x;
  int lane = t & 63;
  int row = blockIdx.x * 4 + (t >> 6);
  int dir = (row >= kRowsD) ? 1 : 0;
  const float* w = dir ? w1 : w0;
  const float* b = dir ? b1 : b0;
  int e0 = lane * 4;
  float4 v = *(const float4*)&h[(size_t)row * kDM + e0];
  float s = v.x + v.y + v.z + v.w;
#pragma unroll
  for (int o = 32; o > 0; o >>= 1) s += __shfl_xor(s, o);
  float mu = s * (1.0f / kDM);
  float4 d = {v.x - mu, v.y - mu, v.z - mu, v.w - mu};
  float ss = d.x * d.x + d.y * d.y + d.z * d.z + d.w * d.w;
#pragma unroll
  for (int o = 32; o > 0; o >>= 1) ss += __shfl_xor(ss, o);
  float r = rsqrtf(ss * (1.0f / kDM) + 1e-5f);
  float4 wv = *(const float4*)&w[e0];
  float4 bv = *(const float4*)&b[e0];
  ushort4 o = {f2b(d.x * r * wv.x + bv.x), f2b(d.y * r * wv.y + bv.y),
               f2b(d.z * r * wv.z + bv.z), f2b(d.w * r * wv.w + bv.w)};
  *(ushort4*)&xn[(size_t)row * kDM + e0] = o;
}

// ---------------- 128x128 bf16 MFMA GEMM (in_proj), BK=64, XCD m-major ----------------
__global__ __launch_bounds__(256) void gemm_bf16(const ushort* __restrict__ A,
                                                 const ushort* __restrict__ W0,
                                                 const ushort* __restrict__ W1,
                                                 ushort* __restrict__ C16,
                                                 float* __restrict__ dtraw, int Md,
                                                 int N, int K, int NT) {
  int dir = blockIdx.z;
  const ushort* W = dir ? W1 : W0;
  const ushort* Ab = A + (size_t)dir * Md * K;
  int wg = blockIdx.x;
  int chunk = gridDim.x >> 3;
  int swz = (wg & 7) * chunk + (wg >> 3);
  int m0 = (swz / NT) * 128;
  int n0 = (swz % NT) * 128;
  __shared__ __align__(16) ushort As[2][128 * 32];
  __shared__ __align__(16) ushort Ws[2][128 * 32];
  int tid = threadIdx.x;
  int lane = tid & 63;
  int wv = tid >> 6;
  int wr = (wv >> 1) * 64, wc = (wv & 1) * 64;
  int l16 = lane & 15, lk = lane >> 4;
  int rA = tid >> 2;
  int cA = (tid & 3) * 8;
  int rb0 = n0 + rA;       if (rb0 >= N) rb0 = N - 1;
  int rb1 = n0 + rA + 64;  if (rb1 >= N) rb1 = N - 1;

  f32x4 acc[4][4];
#pragma unroll
  for (int m = 0; m < 4; m++)
#pragma unroll
    for (int n = 0; n < 4; n++) acc[m][n] = {0.f, 0.f, 0.f, 0.f};

  for (int k0 = 0; k0 < K; k0 += 64) {
#pragma unroll
    for (int hh = 0; hh < 2; hh++) {
      int kk = k0 + hh * 32;
      gl_lds16(Ab + (size_t)(m0 + rA) * K + kk + cA, (char*)As[hh] + wv * 1024);
      gl_lds16(Ab + (size_t)(m0 + rA + 64) * K + kk + cA,
               (char*)As[hh] + 4096 + wv * 1024);
      gl_lds16(W + (size_t)rb0 * K + kk + cA, (char*)Ws[hh] + wv * 1024);
      gl_lds16(W + (size_t)rb1 * K + kk + cA, (char*)Ws[hh] + 4096 + wv * 1024);
    }
    __syncthreads();
#pragma unroll
    for (int hh = 0; hh < 2; hh++) {
      bf16x8 a[4], b[4];
#pragma unroll
      for (int m = 0; m < 4; m++)
        a[m] = *(const bf16x8*)((const char*)As[hh] +
                                (((wr + m * 16 + l16) * 32 + lk * 8) << 1));
#pragma unroll
      for (int n = 0; n < 4; n++)
        b[n] = *(const bf16x8*)((const char*)Ws[hh] +
                                (((wc + n * 16 + l16) * 32 + lk * 8) << 1));
#pragma unroll
      for (int m = 0; m < 4; m++)
#pragma unroll
        for (int n = 0; n < 4; n++)
          acc[m][n] =
              __builtin_amdgcn_mfma_f32_16x16x32_bf16(a[m], b[n], acc[m][n], 0, 0, 0);
    }
    __syncthreads();
  }
  ushort* Cb = C16 + (size_t)dir * Md * N;
  float* dtb = dtraw + (size_t)dir * Md * kNH;
#pragma unroll
  for (int m = 0; m < 4; m++) {
#pragma unroll
    for (int n = 0; n < 4; n++) {
      int col = n0 + wc + n * 16 + l16;
      if (col < N) {
#pragma unroll
        for (int r = 0; r < 4; r++) {
          int row = m0 + wr + m * 16 + lk * 4 + r;
          float v = acc[m][n][r];
          Cb[(size_t)row * N + col] = f2b(v);
          if (col >= 2 * kDI + 2 * kDS)
            dtb[(size_t)row * kNH + (col - (2 * kDI + 2 * kDS))] = v;
        }
      }
    }
  }
}

// ---------------- 64x64 bf16 MFMA GEMM (out_proj / fusion), BK=64 ----------------
// accumulate==1: C += rsqrt(rsum/512+eps) * acc   (RMS scale in epilogue)
__global__ __launch_bounds__(256) void gemm_bf16_64(const ushort* __restrict__ A,
                                                    const ushort* __restrict__ W0,
                                                    const ushort* __restrict__ W1,
                                                    float* __restrict__ C,
                                                    const float* __restrict__ rsum,
                                                    int Md, int N, int K, int NT,
                                                    int accumulate) {
  int dir = blockIdx.z;
  const ushort* W = dir ? W1 : W0;
  const ushort* Ab = A + (size_t)dir * Md * K;
  float* Cb = C + (size_t)dir * Md * N;
  int wg = blockIdx.x;
  int chunk = gridDim.x >> 3;
  int swz = (wg & 7) * chunk + (wg >> 3);
  int m0 = (swz / NT) * 64;
  int n0 = (swz % NT) * 64;
  __shared__ __align__(16) ushort As[2][64 * 32];
  __shared__ __align__(16) ushort Ws[2][64 * 32];
  int tid = threadIdx.x;
  int lane = tid & 63;
  int wv = tid >> 6;
  int wr = (wv >> 1) * 32, wc = (wv & 1) * 32;
  int l16 = lane & 15, lk = lane >> 4;
  int rA = tid >> 2;
  int cA = (tid & 3) * 8;

  f32x4 acc[2][2];
#pragma unroll
  for (int m = 0; m < 2; m++)
#pragma unroll
    for (int n = 0; n < 2; n++) acc[m][n] = {0.f, 0.f, 0.f, 0.f};

  for (int k0 = 0; k0 < K; k0 += 64) {
#pragma unroll
    for (int hh = 0; hh < 2; hh++) {
      int kk = k0 + hh * 32;
      gl_lds16(Ab + (size_t)(m0 + rA) * K + kk + cA, (char*)As[hh] + wv * 1024);
      gl_lds16(W + (size_t)(n0 + rA) * K + kk + cA, (char*)Ws[hh] + wv * 1024);
    }
    __syncthreads();
#pragma unroll
    for (int hh = 0; hh < 2; hh++) {
      bf16x8 a[2], b[2];
#pragma unroll
      for (int m = 0; m < 2; m++)
        a[m] = *(const bf16x8*)((const char*)As[hh] +
                                (((wr + m * 16 + l16) * 32 + lk * 8) << 1));
#pragma unroll
      for (int n = 0; n < 2; n++)
        b[n] = *(const bf16x8*)((const char*)Ws[hh] +
                                (((wc + n * 16 + l16) * 32 + lk * 8) << 1));
#pragma unroll
      for (int m = 0; m < 2; m++)
#pragma unroll
        for (int n = 0; n < 2; n++)
          acc[m][n] =
              __builtin_amdgcn_mfma_f32_16x16x32_bf16(a[m], b[n], acc[m][n], 0, 0, 0);
    }
    __syncthreads();
  }
#pragma unroll
  for (int m = 0; m < 2; m++) {
#pragma unroll
    for (int r = 0; r < 4; r++) {
      int row = m0 + wr + m * 16 + lk * 4 + r;
      float sc = 1.f;
      if (accumulate)
        sc = rsqrtf(rsum[(size_t)dir * Md + row] * (1.0f / kDI) + 1e-5f);
#pragma unroll
      for (int n = 0; n < 2; n++) {
        int col = n0 + wc + n * 16 + l16;
        size_t idx = (size_t)row * N + col;
        float v = acc[m][n][r];
        if (accumulate) Cb[idx] += sc * v;
        else Cb[idx] = v;
      }
    }
  }
}

// ---------------- merged: conv+silu (8 ch/thread) | softplus+cumsum ----------------
constexpr int kConvBlocks = (kRows / 16) * (kCDIM / 8) / 256;  // 320

__global__ __launch_bounds__(256) void conv_cumsum_kernel(
    const ushort* __restrict__ zxb, const float* __restrict__ cw0,
    const float* __restrict__ cb0, const float* __restrict__ cw1,
    const float* __restrict__ cb1, ushort* __restrict__ xcb,
    const float* __restrict__ dtraw, const float* __restrict__ db0,
    const float* __restrict__ db1, const float* __restrict__ al0,
    const float* __restrict__ al1, float* __restrict__ dt,
    float* __restrict__ cs, float* __restrict__ g) {
  if ((int)blockIdx.x < kConvBlocks) {
    constexpr int kCG = kCDIM / 8;  // 80 channel groups
    int idx = blockIdx.x * 256 + threadIdx.x;
    int c8 = (idx % kCG) * 8;
    int rt = idx / kCG;
    int bb = rt >> 7;
    int l0 = (rt & 127) << 4;
    int dir = bb >> 2;
    const float* cw = dir ? cw1 : cw0;
    const float* cb = dir ? cb1 : cb0;
    float wt[8][4];
#pragma unroll
    for (int c = 0; c < 8; c++) {
      float4 w = *(const float4*)&cw[(c8 + c) * 4];
      wt[c][0] = w.x; wt[c][1] = w.y; wt[c][2] = w.z; wt[c][3] = w.w;
    }
    float bias[8];
    {
      float4 b0 = *(const float4*)&cb[c8];
      float4 b1 = *(const float4*)&cb[c8 + 4];
      bias[0] = b0.x; bias[1] = b0.y; bias[2] = b0.z; bias[3] = b0.w;
      bias[4] = b1.x; bias[5] = b1.y; bias[6] = b1.z; bias[7] = b1.w;
    }
    const ushort* base = zxb + ((size_t)(bb * kL)) * kDPROJ + kDI + c8;
    float w0[8], w1[8], w2[8];
    if (l0 == 0) {
#pragma unroll
      for (int c = 0; c < 8; c++) { w0[c] = 0.f; w1[c] = 0.f; w2[c] = 0.f; }
    } else {
      U16x8 a, b, c;
      a.v = *(const int4*)(base + (size_t)(l0 - 3) * kDPROJ);
      b.v = *(const int4*)(base + (size_t)(l0 - 2) * kDPROJ);
      c.v = *(const int4*)(base + (size_t)(l0 - 1) * kDPROJ);
#pragma unroll
      for (int q = 0; q < 8; q++) {
        w0[q] = b2f(a.u[q]); w1[q] = b2f(b.u[q]); w2[q] = b2f(c.u[q]);
      }
    }
    ushort* outp = xcb + (size_t)(bb * kL + l0) * kCDIM + c8;
#pragma unroll
    for (int r = 0; r < 16; r++) {
      U16x8 cu;
      cu.v = *(const int4*)(base + (size_t)(l0 + r) * kDPROJ);
      U16x8 o;
#pragma unroll
      for (int c = 0; c < 8; c++) {
        float cf = b2f(cu.u[c]);
        float a = bias[c] + wt[c][0] * w0[c] + wt[c][1] * w1[c] + wt[c][2] * w2[c] +
                  wt[c][3] * cf;
        o.u[c] = f2b(a / (1.f + __expf(-a)));
        w0[c] = w1[c];
        w1[c] = w2[c];
        w2[c] = cf;
      }
      *(int4*)(outp + (size_t)r * kCDIM) = o.v;
    }
  } else {
    int t = threadIdx.x;
    int c = t & 63;
    int wid = ((int)blockIdx.x - kConvBlocks) * 4 + (t >> 6);
    int h = wid & (kNH - 1);
    int k = (wid >> 4) & (kKC - 1);
    int bb = wid >> 9;
    int dir = bb >> 2;
    int row = bb * kL + k * kCH + c;
    float x = dtraw[(size_t)row * kNH + h] + (dir ? db1 : db0)[h];
    float dtv = (x > 20.f) ? x : log1pf(expf(x));
    dt[(size_t)row * kNH + h] = dtv;
    float A = -__expf((dir ? al1 : al0)[h]);
    float s = dtv * A;
#pragma unroll
    for (int off = 1; off < 64; off <<= 1) {
      float u = __shfl_up(s, off);
      if (c >= off) s += u;
    }
    cs[(size_t)wid * kCH + c] = s;
    if (c == 63) g[wid] = __expf(s);
  }
}

// ---------------- MFMA states: 2 blocks per (b,k), wave per head; bf16 out ----------------
__global__ __launch_bounds__(256) void states_kernel(const ushort* __restrict__ xcb,
                                                     const float* __restrict__ dt,
                                                     const float* __restrict__ cs,
                                                     ushort* __restrict__ states) {
  int bid = blockIdx.x;
  int half = bid & 1;
  int bk = bid >> 1;
  int k = bk & (kKC - 1);
  int bb = bk >> 5;
  __shared__ __align__(16) ushort Bstage[64][72];
  __shared__ __align__(16) ushort Bt[64][72];
  __shared__ __align__(16) ushort Ap[4][32][72];
  __shared__ float w_s[8][64];
  int t = threadIdx.x;
  int lane = t & 63, wv = t >> 6;
  size_t rowbase = (size_t)(bb * kL + k * kCH);
  {
    int j = t >> 2, n0 = (t & 3) * 16;
    const ushort* src = xcb + (rowbase + j) * kCDIM + kDI + n0;
    *(int4*)&Bstage[j][n0] = *(const int4*)src;
    *(int4*)&Bstage[j][n0 + 8] = *(const int4*)(src + 8);
  }
#pragma unroll
  for (int i = 0; i < 2; i++) {
    int e = t + i * 256;
    int hl = e >> 6, c = e & 63;
    int h = half * 8 + hl;
    const float* csb = cs + ((size_t)bk * 16 + h) * kCH;
    w_s[hl][c] = __expf(csb[63] - csb[c]) * dt[(rowbase + c) * kNH + h];
  }
  __syncthreads();
#pragma unroll
  for (int i = 0; i < 16; i++) {
    int e = t + i * 256;
    int j = e & 63, n = e >> 6;
    Bt[n][j] = Bstage[j][n];
  }
  __syncthreads();
  int l15 = lane & 15, lk8 = (lane >> 4) * 8;
  for (int hg = 0; hg < 2; hg++) {
    int hl = hg * 4 + wv;
    int h = half * 8 + hl;
    float wl = w_s[hl][lane];
    const ushort* xrow = xcb + (rowbase + lane) * kCDIM + h * 32;
#pragma unroll
    for (int q4 = 0; q4 < 4; q4++) {
      U16x8 v;
      v.v = *(const int4*)(xrow + q4 * 8);
#pragma unroll
      for (int q = 0; q < 8; q++)
        Ap[wv][q4 * 8 + q][lane] = f2b(b2f(v.u[q]) * wl);
    }
#pragma unroll
    for (int pt = 0; pt < 2; pt++) {
#pragma unroll
      for (int nt = 0; nt < 4; nt++) {
        f32x4 acc = {0.f, 0.f, 0.f, 0.f};
#pragma unroll
        for (int kt = 0; kt < 2; kt++) {
          bf16x8 a = *(const bf16x8*)&Ap[wv][pt * 16 + l15][kt * 32 + lk8];
          bf16x8 b = *(const bf16x8*)&Bt[nt * 16 + l15][kt * 32 + lk8];
          acc = __builtin_amdgcn_mfma_f32_16x16x32_bf16(a, b, acc, 0, 0, 0);
        }
        size_t base = ((size_t)bk * 16 + h) * 2048;
#pragma unroll
        for (int r = 0; r < 4; r++) {
          int p = pt * 16 + (lane >> 4) * 4 + r;
          states[base + p * 64 + nt * 16 + l15] = f2b(acc[r]);
        }
      }
    }
  }
}

// ---------------- chunk scan (x4, prefetched) + rsum zeroing ----------------
__global__ __launch_bounds__(256) void scan_kernel(const ushort* __restrict__ st,
                                                   const float* __restrict__ g,
                                                   ushort* __restrict__ spbf,
                                                   float* __restrict__ rsum) {
  if ((int)blockIdx.x >= 256) {
    int i2 = ((int)blockIdx.x - 256) * 1024 + threadIdx.x * 4;
    float4 z = {0.f, 0.f, 0.f, 0.f};
    *(float4*)&rsum[i2] = z;
    return;
  }
  int idx = blockIdx.x * 256 + threadIdx.x;
  int pn4 = (idx & 511) * 4;
  int h = (idx >> 9) & (kNH - 1);
  int bb = idx >> 13;
  size_t base = ((size_t)(bb * kKC) * kNH + h) * 2048 + pn4;
  size_t stride = (size_t)kNH * 2048;
  const float* gp = g + bb * kKC * kNH + h;
  float S[4] = {0.f, 0.f, 0.f, 0.f};
  ushort4 sv = *(const ushort4*)&st[base];
  float gk = gp[0];
  for (int k = 0; k < kKC; k++) {
    size_t off = base + (size_t)k * stride;
    ushort4 so = {f2b(S[0]), f2b(S[1]), f2b(S[2]), f2b(S[3])};
    *(ushort4*)&spbf[off] = so;
    ushort4 nxt;
    float gn = 0.f;
    if (k < kKC - 1) {
      nxt = *(const ushort4*)&st[off + stride];
      gn = gp[(k + 1) * kNH];
    }
    S[0] = gk * S[0] + b2f(sv.x);
    S[1] = gk * S[1] + b2f(sv.y);
    S[2] = gk * S[2] + b2f(sv.z);
    S[3] = gk * S[3] + b2f(sv.w);
    sv = nxt;
    gk = gn;
  }
}

// ---------------- fused y + silu-gate: 4 blocks per (b,k), 4 heads each ----------------
// writes ybf = bf16(y*silu(z)) and atomically accumulates per-row sum(val^2).
__global__ __launch_bounds__(256) void y_kernel(const ushort* __restrict__ xcb,
                                                const ushort* __restrict__ zxb,
                                                const float* __restrict__ dt,
                                                const float* __restrict__ cs,
                                                const ushort* __restrict__ spbf,
                                                const float* __restrict__ D0,
                                                const float* __restrict__ D1,
                                                float* __restrict__ rsum,
                                                ushort* __restrict__ ybf) {
  int bid = blockIdx.x;
  int hq = bid & 3;
  int bk = bid >> 2;
  int k = bk & (kKC - 1);
  int bb = bk >> 5;
  int dir = bb >> 2;
  __shared__ __align__(16) ushort Cls[64][72];
  __shared__ __align__(16) ushort Bls[64][72];
  __shared__ float CBT[64][67];
  __shared__ __align__(16) ushort xs_s[64][40];
  __shared__ __align__(16) ushort xsT[32][72];
  __shared__ __align__(16) ushort sp_s[32][72];
  __shared__ float cs_s[64], dt_s[64], ecs_s[64];
  int t = threadIdx.x, lane = t & 63, wv = t >> 6;
  int l15 = lane & 15, lk8 = (lane >> 4) * 8;
  size_t rowbase = (size_t)(bb * kL + k * kCH);
  {
    int j = t >> 2, n0 = (t & 3) * 16;
    const ushort* pB = xcb + (rowbase + j) * kCDIM + kDI;
    *(int4*)&Bls[j][n0] = *(const int4*)(pB + n0);
    *(int4*)&Bls[j][n0 + 8] = *(const int4*)(pB + n0 + 8);
    *(int4*)&Cls[j][n0] = *(const int4*)(pB + kDS + n0);
    *(int4*)&Cls[j][n0 + 8] = *(const int4*)(pB + kDS + n0 + 8);
  }
  __syncthreads();
  {
    int i0 = wv * 16;
#pragma unroll
    for (int jt = 0; jt < 4; jt++) {
      f32x4 acc = {0.f, 0.f, 0.f, 0.f};
#pragma unroll
      for (int kt = 0; kt < 2; kt++) {
        bf16x8 a = *(const bf16x8*)&Cls[i0 + l15][kt * 32 + lk8];
        bf16x8 b = *(const bf16x8*)&Bls[jt * 16 + l15][kt * 32 + lk8];
        acc = __builtin_amdgcn_mfma_f32_16x16x32_bf16(a, b, acc, 0, 0, 0);
      }
#pragma unroll
      for (int r = 0; r < 4; r++)
        CBT[jt * 16 + l15][i0 + (lane >> 4) * 4 + r] = acc[r];
    }
  }
  float ssr[4] = {0.f, 0.f, 0.f, 0.f};  // per-row sum(val^2), rows fixed per thread
  for (int hi = 0; hi < 4; hi++) {
    int h = hq * 4 + hi;
    int bkh = bk * 16 + h;
    float Dp = (dir ? D1 : D0)[h];
    __syncthreads();
    {
      int j = t >> 2, p0 = (t & 3) * 8;
      U16x8 v;
      v.v = *(const int4*)(xcb + (rowbase + j) * kCDIM + h * 32 + p0);
      *(int4*)&xs_s[j][p0] = v.v;
#pragma unroll
      for (int q = 0; q < 8; q++) xsT[p0 + q][j] = v.u[q];
      int4 s = *(const int4*)(spbf + (size_t)bkh * 2048 + t * 8);
      *(int4*)&sp_s[t >> 3][(t & 7) * 8] = s;
      if (t < 64) {
        float cv = cs[(size_t)bkh * kCH + t];
        cs_s[t] = cv;
        ecs_s[t] = __expf(cv);
        dt_s[t] = dt[(rowbase + t) * kNH + h];
      }
    }
    __syncthreads();
    int i0 = wv * 16;
    int ia = i0 + l15;
    float csi = cs_s[ia];
    U16x8 af[2];
#pragma unroll
    for (int kt = 0; kt < 2; kt++) {
#pragma unroll
      for (int q = 0; q < 8; q++) {
        int j = kt * 32 + lk8 + q;
        float v = 0.f;
        if (j <= ia) v = __expf(csi - cs_s[j]) * dt_s[j] * CBT[j][ia];
        af[kt].u[q] = f2b(v);
      }
    }
#pragma unroll
    for (int pt = 0; pt < 2; pt++) {
      f32x4 acc = {0.f, 0.f, 0.f, 0.f};
      f32x4 acc2 = {0.f, 0.f, 0.f, 0.f};
#pragma unroll
      for (int kt = 0; kt < 2; kt++) {
        bf16x8 bx = *(const bf16x8*)&xsT[pt * 16 + l15][kt * 32 + lk8];
        acc = __builtin_amdgcn_mfma_f32_16x16x32_bf16(af[kt].b, bx, acc, 0, 0, 0);
        bf16x8 ac = *(const bf16x8*)&Cls[i0 + l15][kt * 32 + lk8];
        bf16x8 bs = *(const bf16x8*)&sp_s[pt * 16 + l15][kt * 32 + lk8];
        acc2 = __builtin_amdgcn_mfma_f32_16x16x32_bf16(ac, bs, acc2, 0, 0, 0);
      }
#pragma unroll
      for (int r = 0; r < 4; r++) {
        int io = i0 + (lane >> 4) * 4 + r;
        int p = pt * 16 + l15;
        float xsv = b2f(xs_s[io][p]);
        float v = acc[r] + ecs_s[io] * acc2[r] + Dp * xsv;
        float z = b2f(zxb[(rowbase + io) * kDPROJ + h * 32 + p]);
        float gz = z / (1.f + __expf(-z));
        float val = v * gz;
        ybf[(rowbase + io) * kDI + h * 32 + p] = f2b(val);
        ssr[r] += val * val;
      }
    }
  }
  // reduce ssr across the 16 lanes (l15) that share each row, then atomicAdd.
#pragma unroll
  for (int o = 1; o < 16; o <<= 1) {
#pragma unroll
    for (int r = 0; r < 4; r++) ssr[r] += __shfl_xor(ssr[r], o);
  }
  if (l15 == 0) {
    int i0 = wv * 16;
#pragma unroll
    for (int r = 0; r < 4; r++) {
      int io = i0 + (lane >> 4) * 4 + r;
      atomicAdd(&rsum[rowbase + io], ssr[r]);
    }
  }
}

// ---------------- hcat bf16 ----------------
__global__ __launch_bounds__(256) void concat_kernel(const float* __restrict__ h,
                                                     ushort* __restrict__ hcat) {
  int idx = blockIdx.x * 256 + threadIdx.x;
  if (idx >= 4 * kL * 2 * kDM) return;
  int e = idx & 511;
  int l = (idx >> 9) & (kL - 1);
  int b = idx >> 20;
  float v;
  if (e < kDM)
    v = h[((size_t)(b * kL + l)) * kDM + e];
  else
    v = h[((size_t)((4 + b) * kL + (kL - 1 - l))) * kDM + (e - kDM)];
  hcat[idx] = f2b(v);
}

}  // namespace

extern "C" void kernel_launch(void* const* d_in, const int* in_sizes, int n_in,
                              void* d_out, int out_size, void* d_ws, size_t ws_size,
                              hipStream_t stream) {
  const float* x = (const float*)d_in[0];
  const float* fw_ln_w = (const float*)d_in[1];
  const float* fw_ln_b = (const float*)d_in[2];
  const float* fw_win = (const float*)d_in[3];
  const float* fw_convw = (const float*)d_in[4];
  const float* fw_convb = (const float*)d_in[5];
  const float* fw_alog = (const float*)d_in[6];
  const float* fw_dtb = (const float*)d_in[7];
  const float* fw_D = (const float*)d_in[8];
  const float* fw_nw = (const float*)d_in[9];
  const float* fw_wout = (const float*)d_in[10];
  const float* bw_ln_w = (const float*)d_in[11];
  const float* bw_ln_b = (const float*)d_in[12];
  const float* bw_win = (const float*)d_in[13];
  const float* bw_convw = (const float*)d_in[14];
  const float* bw_convb = (const float*)d_in[15];
  const float* bw_alog = (const float*)d_in[16];
  const float* bw_dtb = (const float*)d_in[17];
  const float* bw_D = (const float*)d_in[18];
  const float* bw_nw = (const float*)d_in[19];
  const float* bw_wout = (const float*)d_in[20];
  const float* fusion_w = (const float*)d_in[21];
  float* out = (float*)d_out;

  float* ws = (float*)d_ws;
  float* h = ws;                                   // 16384*256 f32
  float* dtraw = h + (size_t)kRows * kDM;          // 16384*16 f32
  float* dt = dtraw + (size_t)kRows * kNH;         // 16384*16 f32
  float* cs = dt + (size_t)kRows * kNH;            // 4096*64 f32
  float* g = cs + (size_t)kBB * kKC * kNH * kCH;   // 4096 f32
  float* rsum = g + (size_t)kBB * kKC * kNH;       // 16384 f32
  ushort* zxb = (ushort*)(rsum + kRows);           // 16384*1168 bf16
  ushort* xcb = zxb + (size_t)kRows * kDPROJ;      // 16384*640
  ushort* states = xcb + (size_t)kRows * kCDIM;    // 4096*2048
  ushort* spbf = states + (size_t)kBB * kKC * kNH * 2048;  // 4096*2048
  ushort* xnbf = spbf + (size_t)kBB * kKC * kNH * 2048;    // 16384*256 (also hcat)
  ushort* ybf = xnbf + (size_t)kRows * kDM;                // 16384*512
  ushort* winbf = ybf + (size_t)kRows * kDI;               // 2*8*1168*256 (+fusion)
  ushort* fusbf = winbf + (size_t)2 * 8 * kDPROJ * kDM;    // 256*512
  ushort* woutbf = fusbf + (size_t)kDM * kDI;              // 2*8*256*512
  ushort* hcatbf = xnbf;

  f2b_all_kernel<<<(kQtot + 255) / 256, 256, 0, stream>>>(fw_win, bw_win, fusion_w,
                                                          winbf);
  wout_f2b_kernel<<<(kQwoutAll + 255) / 256, 256, 0, stream>>>(fw_wout, bw_wout,
                                                               fw_nw, bw_nw, woutbf);
  init_h_kernel<<<(4 * kL * kDM + 255) / 256, 256, 0, stream>>>(x, h);

  for (int i = 0; i < 8; i++) {
    const size_t oLN = (size_t)i * kDM;
    const size_t oCW = (size_t)i * kCDIM * 4;
    const size_t oCB = (size_t)i * kCDIM;
    const size_t oH = (size_t)i * kNH;
    const ushort* win0 = winbf + (size_t)i * kDPROJ * kDM;
    const ushort* win1 = winbf + (size_t)(8 + i) * kDPROJ * kDM;
    const ushort* wout0 = woutbf + (size_t)i * kDM * kDI;
    const ushort* wout1 = woutbf + (size_t)(8 + i) * kDM * kDI;

    ln_kernel<<<kRows / 4, 256, 0, stream>>>(h, fw_ln_w + oLN, fw_ln_b + oLN,
                                             bw_ln_w + oLN, bw_ln_b + oLN, xnbf);
    {
      dim3 grid(10 * 64, 1, 2);
      gemm_bf16<<<grid, 256, 0, stream>>>(xnbf, win0, win1, zxb, dtraw, kRowsD,
                                          kDPROJ, kDM, 10);
    }
    {
      int cumsumBlocks = kBB * kKC * kNH / 4;
      conv_cumsum_kernel<<<kConvBlocks + cumsumBlocks, 256, 0, stream>>>(
          zxb, fw_convw + oCW, fw_convb + oCB, bw_convw + oCW, bw_convb + oCB, xcb,
          dtraw, fw_dtb + oH, bw_dtb + oH, fw_alog + oH, bw_alog + oH, dt, cs, g);
    }
    states_kernel<<<kBB * kKC * 2, 256, 0, stream>>>(xcb, dt, cs, states);
    scan_kernel<<<256 + 16, 256, 0, stream>>>(states, g, spbf, rsum);
    y_kernel<<<kBB * kKC * 4, 256, 0, stream>>>(xcb, zxb, dt, cs, spbf, fw_D + oH,
                                                bw_D + oH, rsum, ybf);
    {
      dim3 grid(4 * 128, 1, 2);
      gemm_bf16_64<<<grid, 256, 0, stream>>>(ybf, wout0, wout1, h, rsum, kRowsD,
                                             kDM, kDI, 4, 1);
    }
  }

  concat_kernel<<<(4 * kL * 2 * kDM + 255) / 256, 256, 0, stream>>>(h, hcatbf);
  {
    dim3 grid(4 * 128, 1, 1);
    gemm_bf16_64<<<grid, 256, 0, stream>>>(hcatbf, fusbf, fusbf, out, nullptr,
                                           kRowsD, kDM, 2 * kDM, 4, 0);
  }
}